// Round 10
// baseline (256.509 us; speedup 1.0000x reference)
//
#include <hip/hip_runtime.h>
#include <math.h>

typedef unsigned short u16;
typedef unsigned int u32;
typedef short s16x8 __attribute__((ext_vector_type(8)));   // 8 bf16 (4 VGPRs)
typedef float f32x4 __attribute__((ext_vector_type(4)));   // 4 fp32
typedef float f32x16 __attribute__((ext_vector_type(16))); // 16 fp32 (32x32 acc)

static constexpr int Cc = 256;
static constexpr int Ll = 4096;
static constexpr int Bb = 4;

__device__ __forceinline__ u16 f2b(float f) {
    union { float f; unsigned u; } v; v.f = f;
    unsigned r = v.u + 0x7FFF + ((v.u >> 16) & 1);   // RNE
    return (u16)(r >> 16);
}
__device__ __forceinline__ float b2f(u16 h) {
    union { unsigned u; float f; } v; v.u = ((unsigned)h) << 16; return v.f;
}

// async 16B global->LDS (lds dest = wave-uniform base + lane*16)
__device__ __forceinline__ void gload_lds16(const u16* g, u16* l) {
    __builtin_amdgcn_global_load_lds(
        (const __attribute__((address_space(1))) u32*)g,
        (__attribute__((address_space(3))) u32*)l, 16, 0, 0);
}

// ---------------- Kernel 3': transpose + fused BN partial stats ----------------
// x [B][C][L] fp32 -> XT [B][L][C] bf16; also atomicAdd per-channel sum/sumsq
// (from the bf16-rounded tile; stats error ~3e-5, far below tolerance).
__global__ void k_transpose(const float* __restrict__ x, u16* __restrict__ XT,
                            float* __restrict__ sums) {
    int lt = blockIdx.x, ct = blockIdx.y, b = blockIdx.z, t = threadIdx.x;
    int l0 = lt * 64, c0 = ct * 64;
    __shared__ u16 tile[64][65];
    __shared__ float red[2][4][64];
    int ll = t & 63, cb = t >> 6;
    #pragma unroll
    for (int rep = 0; rep < 16; rep++) {
        int cl = cb * 16 + rep;
        tile[cl][ll] = f2b(x[(size_t)(b * Cc + c0 + cl) * Ll + l0 + ll]);
    }
    __syncthreads();
    int cl2 = t & 63, lb = t >> 6;
    float s = 0.f, s2 = 0.f;
    #pragma unroll
    for (int rep = 0; rep < 16; rep++) {
        int ll2 = lb * 16 + rep;
        u16 hv = tile[cl2][ll2];
        XT[(size_t)(b * Ll + l0 + ll2) * Cc + c0 + cl2] = hv;
        float v = b2f(hv);
        s += v; s2 += v * v;
    }
    red[0][lb][cl2] = s;
    red[1][lb][cl2] = s2;
    __syncthreads();
    if (t < 64) {
        float ss = red[0][0][t] + red[0][1][t] + red[0][2][t] + red[0][3][t];
        float ss2 = red[1][0][t] + red[1][1][t] + red[1][2][t] + red[1][3][t];
        atomicAdd(&sums[c0 + t], ss);
        atomicAdd(&sums[256 + c0 + t], ss2);
    }
}

// ---------------- Kernel 2': fold BN into weights (coefs inline from sums) -----
__global__ void k_fold(const float* __restrict__ wq, const float* __restrict__ bq,
                       const float* __restrict__ wk, const float* __restrict__ bk,
                       const float* __restrict__ wv, const float* __restrict__ bv,
                       const float* __restrict__ wp,
                       const float* __restrict__ gamma, const float* __restrict__ beta,
                       const float* __restrict__ sums,
                       u16* __restrict__ Wqkv, float* __restrict__ biasQKV,
                       u16* __restrict__ Wp16) {
    int m = blockIdx.x, t = threadIdx.x;
    if (m >= 768) {
        int row = m - 768;
        Wp16[row * Cc + t] = f2b(wp[row * Cc + t]);
        return;
    }
    const float inv_n = 1.f / (Bb * Ll);
    float mean = sums[t] * inv_n;
    float var  = sums[256 + t] * inv_n - mean * mean;   // biased, as torch BN
    float rstd = rsqrtf(var + 1e-5f);
    float a  = gamma[t] * rstd;          // coefA
    float cB = beta[t] - mean * a;       // coefB
    int type = m >> 8, row = m & 255;
    const float* W  = (type == 0) ? wq : (type == 1) ? wk : wv;
    const float* bs = (type == 0) ? bq : (type == 1) ? bk : bv;
    float wval = W[row * Cc + t];
    float s2 = (type == 0) ? 0.09016844005556021f : 1.0f;  // (1/sqrt(C)) * log2(e)
    Wqkv[m * Cc + t] = f2b(wval * a * s2);
    __shared__ float rs[256];
    rs[t] = wval * cB;
    __syncthreads();
    for (int off = 128; off > 0; off >>= 1) {
        if (t < off) rs[t] += rs[t + off];
        __syncthreads();
    }
    if (t == 0) biasQKV[m] = (bs[row] + rs[0]) * s2;
}

// ---------------- Kernel 4': QKV GEMM, XT staged once, loop over o-tiles ------
__launch_bounds__(256, 2)
__global__ void k_qkv(const u16* __restrict__ XT, const u16* __restrict__ Wqkv,
                      const float* __restrict__ biasQKV,
                      u16* __restrict__ QT, u16* __restrict__ KT, u16* __restrict__ V) {
    int ly = blockIdx.x, b = blockIdx.y;
    int t = threadIdx.x, w = t >> 6, lane = t & 63;
    int l16 = lane & 15, quad = lane >> 4;
    int l0 = ly * 64;
    __shared__ u16 Xs[64][264];
    {
        int row = t >> 2, chunk = t & 3;
        const u16* src = XT + (size_t)(b * Ll + l0 + row) * Cc + chunk * 64;
        u16* dst = &Xs[row][chunk * 64];
        #pragma unroll
        for (int u = 0; u < 8; u++)
            *(uint4*)(dst + u * 8) = *(const uint4*)(src + u * 8);
    }
    __syncthreads();
    for (int ox = 0; ox < 12; ox++) {
        int o0 = ox * 64;
        s16x8 af[8];
        {
            const u16* wrow = Wqkv + (size_t)(o0 + w * 16 + l16) * Cc + quad * 8;
            #pragma unroll
            for (int ks = 0; ks < 8; ks++) af[ks] = *(const s16x8*)(wrow + ks * 32);
        }
        f32x4 acc[4];
        #pragma unroll
        for (int ns = 0; ns < 4; ns++)
            #pragma unroll
            for (int r = 0; r < 4; r++) acc[ns][r] = 0.f;
        #pragma unroll
        for (int ks = 0; ks < 8; ks++) {
            #pragma unroll
            for (int ns = 0; ns < 4; ns++) {
                s16x8 bf = *(const s16x8*)(&Xs[ns * 16 + l16][ks * 32 + quad * 8]);
                acc[ns] = __builtin_amdgcn_mfma_f32_16x16x32_bf16(af[ks], bf, acc[ns], 0, 0, 0);
            }
        }
        int obase = o0 + w * 16 + quad * 4;
        float bias[4];
        #pragma unroll
        for (int r = 0; r < 4; r++) bias[r] = biasQKV[obase + r];
        #pragma unroll
        for (int ns = 0; ns < 4; ns++) {
            int l = l0 + ns * 16 + l16;
            if (ox < 8) {
                u16* dstbase = (ox < 4) ? QT : KT;
                int oo = obase - ((ox < 4) ? 0 : 256);
                ushort4 pk;
                pk.x = f2b(acc[ns][0] + bias[0]);
                pk.y = f2b(acc[ns][1] + bias[1]);
                pk.z = f2b(acc[ns][2] + bias[2]);
                pk.w = f2b(acc[ns][3] + bias[3]);
                *(ushort4*)(dstbase + (size_t)(b * Ll + l) * Cc + oo) = pk;
            } else {
                #pragma unroll
                for (int r = 0; r < 4; r++) {
                    int o = obase + r - 512;
                    V[(size_t)(b * Cc + o) * Ll + l] = f2b(acc[ns][r] + bias[r]);
                }
            }
        }
    }
}

// ---------------- Kernel 5: flash attention, split-j, 32x32x16 MFMA ------------
// Round-10 deltas: lsum accumulated in C-layout fp32 regs (epilogue reduction,
// removes 64 VALU/iter); raw v_exp_f32 via __builtin_amdgcn_exp2f.
__launch_bounds__(256, 2)
__global__ void k_attn(const u16* __restrict__ QT, const u16* __restrict__ KT,
                       const u16* __restrict__ V, u16* __restrict__ Opart,
                       float* __restrict__ Lpart) {
    int id = blockIdx.x;
    int xcd = id & 7, local = id >> 3;
    int b = xcd >> 1;                       // 2 XCDs per batch: K/V L2-resident
    int u = local * 2 + (xcd & 1);          // 0..127
    int itile = u >> 1;
    int jh = u & 1;
    int t = threadIdx.x, w = t >> 6, lane = t & 63;
    int rh = w & 1, ch = w >> 1;
    int l31 = lane & 31, hi = lane >> 5;    // hi = k-half selector in A/B frags

    __shared__ u16 Ka[16384];       // 32KB: 32 frags (ch 0..1 x ks 0..15) of 1KB
    __shared__ u16 Vbuf[16384];     // 32KB: 32 frags (ctile 0..7 x ksj 0..3)
    __shared__ u16 Pss[64 * 72];    // 64x64 P tile, stride 72 (9KB)
    __shared__ float Lred[2][2][32]; // [rh][ch][row] epilogue l partials

    // Q A-frags: rows rh*32+(l31), k = ks*16 + hi*8 + [0..8)
    s16x8 qf[16];
    {
        const u16* qbase = QT + (size_t)(b * Ll + itile * 64 + rh * 32 + l31) * Cc + hi * 8;
        #pragma unroll
        for (int ks = 0; ks < 16; ks++) qf[ks] = *(const s16x8*)(qbase + ks * 16);
    }

    // staging pointers; frag g = R*4 + w
    const u16* kptr[8];
    const u16* vptr[8];
    #pragma unroll
    for (int R = 0; R < 8; R++) {
        int g = R * 4 + w;
        int gch = g >> 4, gks = g & 15;   // K frag: col-tile, k-step
        kptr[R] = KT + (size_t)(b * Ll + jh * 2048 + gch * 32 + l31) * Cc + gks * 16 + hi * 8;
        int gct = g >> 2, gkj = g & 3;    // V frag: c-tile, j-step
        vptr[R] = V + (size_t)(b * Cc + gct * 32 + l31) * Ll + jh * 2048 + gkj * 16 + hi * 8;
    }

    // prologue: issue K(0) and V(0)
    #pragma unroll
    for (int R = 0; R < 8; R++) {
        gload_lds16(kptr[R], &Ka[(size_t)((R * 4 + w) * 64) * 8]);
        kptr[R] += 64 * Cc;
    }
    #pragma unroll
    for (int R = 0; R < 8; R++) {
        gload_lds16(vptr[R], &Vbuf[(size_t)((R * 4 + w) * 64) * 8]);
        vptr[R] += 64;
    }

    f32x16 of16[4];
    #pragma unroll
    for (int ct = 0; ct < 4; ct++)
        #pragma unroll
        for (int r = 0; r < 16; r++) of16[ct][r] = 0.f;
    f32x16 lsr;                      // C-layout l partials: col ch*32+l31, row reg
    #pragma unroll
    for (int r = 0; r < 16; r++) lsr[r] = 0.f;

    __syncthreads();   // P0: drains K(0), V(0)

    for (int it = 0; it < 32; it++) {
        // ---- phase A: S quadrant = Q K^T (two interleaved acc chains) ----
        f32x16 s0, s1;
        #pragma unroll
        for (int r = 0; r < 16; r++) { s0[r] = 0.f; s1[r] = 0.f; }
        #pragma unroll
        for (int ks = 0; ks < 16; ks += 2) {
            s16x8 bf0 = *(const s16x8*)(&Ka[(size_t)((ch * 16 + ks) * 64 + lane) * 8]);
            s16x8 bf1 = *(const s16x8*)(&Ka[(size_t)((ch * 16 + ks + 1) * 64 + lane) * 8]);
            s0 = __builtin_amdgcn_mfma_f32_32x32x16_bf16(qf[ks], bf0, s0, 0, 0, 0);
            s1 = __builtin_amdgcn_mfma_f32_32x32x16_bf16(qf[ks + 1], bf1, s1, 0, 0, 0);
        }
        // ---- softmax (fixed m=0): P = exp2(s); l partial in-register ----
        #pragma unroll
        for (int reg = 0; reg < 16; reg++) {
            float p = __builtin_amdgcn_exp2f(s0[reg] + s1[reg]);
            lsr[reg] += p;
            int row_local = (reg & 3) + 8 * (reg >> 2) + 4 * hi;
            Pss[(rh * 32 + row_local) * 72 + ch * 32 + l31] = f2b(p);
        }
        __syncthreads();   // M: Ka reads done; Pss visible; drains V(it)
        if (it < 31) {
            #pragma unroll
            for (int R = 0; R < 8; R++) {
                gload_lds16(kptr[R], &Ka[(size_t)((R * 4 + w) * 64) * 8]);
                kptr[R] += 64 * Cc;
            }
        }
        // ---- phase B: O += P * V^T ----
        #pragma unroll
        for (int ksj = 0; ksj < 4; ksj++) {
            s16x8 pa = *(const s16x8*)(&Pss[(rh * 32 + l31) * 72 + ksj * 16 + hi * 8]);
            #pragma unroll
            for (int ct = 0; ct < 4; ct++) {
                s16x8 bf = *(const s16x8*)(&Vbuf[(size_t)(((ch * 4 + ct) * 4 + ksj) * 64 + lane) * 8]);
                of16[ct] = __builtin_amdgcn_mfma_f32_32x32x16_bf16(pa, bf, of16[ct], 0, 0, 0);
            }
        }
        __syncthreads();   // B: Vbuf+Pss reads done; drains K(it+1)
        if (it < 31) {
            #pragma unroll
            for (int R = 0; R < 8; R++) {
                gload_lds16(vptr[R], &Vbuf[(size_t)((R * 4 + w) * 64) * 8]);
                vptr[R] += 64;
            }
        }
    }
    // epilogue: reduce lsr across the 32 cols held by this wave's lanes, then
    // combine the two ch waves through LDS.  lanes l31==0 of each half hold sums.
    #pragma unroll
    for (int reg = 0; reg < 16; reg++) {
        float v = lsr[reg];
        #pragma unroll
        for (int off = 16; off > 0; off >>= 1) v += __shfl_xor(v, off);
        int row_local = (reg & 3) + 8 * (reg >> 2) + 4 * hi;
        if (l31 == 0) Lred[rh][ch][row_local] = v;
    }
    __syncthreads();
    int mi0 = ((jh * 4 + b) * 64 + itile) * 64 + rh * 32;
    if (ch == 0 && lane < 32)
        Lpart[mi0 + lane] = Lred[rh][0][lane] + Lred[rh][1][lane];
    #pragma unroll
    for (int ct = 0; ct < 4; ct++) {
        #pragma unroll
        for (int reg = 0; reg < 16; reg++) {
            int row_local = (reg & 3) + 8 * (reg >> 2) + 4 * hi;
            Opart[(size_t)(mi0 + row_local) * 256 + ch * 128 + ct * 32 + l31] =
                f2b(of16[ct][reg]);
        }
    }
}

// ---------------- Kernel 5b (fallback): merge two j-half partials -> OT ---------
__global__ void k_merge(const u16* __restrict__ Opart, const float* __restrict__ Lpart,
                        u16* __restrict__ OT) {
    int id = blockIdx.x, t = threadIdx.x;
    int b = id >> 6, itile = id & 63;
    int row = t >> 2, seg = t & 3;
    size_t i0 = ((size_t)(0 + b) * 64 + itile) * 64 + row;
    size_t i1 = ((size_t)(4 + b) * 64 + itile) * 64 + row;
    float inv = 1.f / (Lpart[i0] + Lpart[i1]);
    const u16* p0 = Opart + i0 * 256 + seg * 64;
    const u16* p1 = Opart + i1 * 256 + seg * 64;
    u16* dst = OT + (size_t)(b * Ll + itile * 64 + row) * Cc + seg * 64;
    #pragma unroll
    for (int k = 0; k < 8; k++) {
        ushort4 a0 = *(const ushort4*)(p0 + k * 8 + 0);
        ushort4 b0 = *(const ushort4*)(p0 + k * 8 + 4);
        ushort4 a1 = *(const ushort4*)(p1 + k * 8 + 0);
        ushort4 b1 = *(const ushort4*)(p1 + k * 8 + 4);
        ushort4 oA, oB;
        oA.x = f2b((b2f(a0.x) + b2f(a1.x)) * inv);
        oA.y = f2b((b2f(a0.y) + b2f(a1.y)) * inv);
        oA.z = f2b((b2f(a0.z) + b2f(a1.z)) * inv);
        oA.w = f2b((b2f(a0.w) + b2f(a1.w)) * inv);
        oB.x = f2b((b2f(b0.x) + b2f(b1.x)) * inv);
        oB.y = f2b((b2f(b0.y) + b2f(b1.y)) * inv);
        oB.z = f2b((b2f(b0.z) + b2f(b1.z)) * inv);
        oB.w = f2b((b2f(b0.w) + b2f(b1.w)) * inv);
        *(ushort4*)(dst + k * 8 + 0) = oA;
        *(ushort4*)(dst + k * 8 + 4) = oB;
    }
}

// ---------------- Kernel 6': projection, OT staged once, loop over o-tiles ------
// fused=1: merge the Opart halves (normalize by l0+l1) during LDS staging.
__launch_bounds__(256, 2)
__global__ void k_proj(const u16* __restrict__ OT, const u16* __restrict__ Opart,
                       const float* __restrict__ Lpart, int fused,
                       const u16* __restrict__ Wp16,
                       const float* __restrict__ bp, const float* __restrict__ x,
                       float* __restrict__ out) {
    int ly = blockIdx.x, b = blockIdx.y;
    int t = threadIdx.x, w = t >> 6, lane = t & 63;
    int l16 = lane & 15, quad = lane >> 4;
    int l0 = ly * 64;
    __shared__ u16 Os[64][264];
    {
        int row = t >> 2, chunk = t & 3;
        u16* dst = &Os[row][chunk * 64];
        if (fused) {
            size_t i0 = ((size_t)(0 + b) * Ll + l0 + row);
            size_t i1 = ((size_t)(4 + b) * Ll + l0 + row);
            float inv = 1.f / (Lpart[i0] + Lpart[i1]);
            const u16* p0 = Opart + i0 * 256 + chunk * 64;
            const u16* p1 = Opart + i1 * 256 + chunk * 64;
            #pragma unroll
            for (int k = 0; k < 8; k++) {
                ushort4 a0 = *(const ushort4*)(p0 + k * 8 + 0);
                ushort4 b0 = *(const ushort4*)(p0 + k * 8 + 4);
                ushort4 a1 = *(const ushort4*)(p1 + k * 8 + 0);
                ushort4 b1 = *(const ushort4*)(p1 + k * 8 + 4);
                ushort4 oA, oB;
                oA.x = f2b((b2f(a0.x) + b2f(a1.x)) * inv);
                oA.y = f2b((b2f(a0.y) + b2f(a1.y)) * inv);
                oA.z = f2b((b2f(a0.z) + b2f(a1.z)) * inv);
                oA.w = f2b((b2f(a0.w) + b2f(a1.w)) * inv);
                oB.x = f2b((b2f(b0.x) + b2f(b1.x)) * inv);
                oB.y = f2b((b2f(b0.y) + b2f(b1.y)) * inv);
                oB.z = f2b((b2f(b0.z) + b2f(b1.z)) * inv);
                oB.w = f2b((b2f(b0.w) + b2f(b1.w)) * inv);
                *(ushort4*)(dst + k * 8 + 0) = oA;
                *(ushort4*)(dst + k * 8 + 4) = oB;
            }
        } else {
            const u16* src = OT + (size_t)(b * Ll + l0 + row) * Cc + chunk * 64;
            #pragma unroll
            for (int u = 0; u < 8; u++)
                *(uint4*)(dst + u * 8) = *(const uint4*)(src + u * 8);
        }
    }
    __syncthreads();
    for (int ox = 0; ox < 4; ox++) {
        int o0 = ox * 64;
        s16x8 af[8];
        {
            const u16* wrow = Wp16 + (size_t)(o0 + w * 16 + l16) * Cc + quad * 8;
            #pragma unroll
            for (int ks = 0; ks < 8; ks++) af[ks] = *(const s16x8*)(wrow + ks * 32);
        }
        f32x4 acc[4];
        #pragma unroll
        for (int ns = 0; ns < 4; ns++)
            #pragma unroll
            for (int r = 0; r < 4; r++) acc[ns][r] = 0.f;
        #pragma unroll
        for (int ks = 0; ks < 8; ks++) {
            #pragma unroll
            for (int ns = 0; ns < 4; ns++) {
                s16x8 bf = *(const s16x8*)(&Os[ns * 16 + l16][ks * 32 + quad * 8]);
                acc[ns] = __builtin_amdgcn_mfma_f32_16x16x32_bf16(af[ks], bf, acc[ns], 0, 0, 0);
            }
        }
        int ob = o0 + w * 16 + quad * 4;
        float bias[4];
        #pragma unroll
        for (int r = 0; r < 4; r++) bias[r] = bp[ob + r];
        #pragma unroll
        for (int ns = 0; ns < 4; ns++) {
            #pragma unroll
            for (int r = 0; r < 4; r++) {
                int o = ob + r;
                int l = l0 + ns * 16 + l16;
                size_t idx = (size_t)(b * Cc + o) * Ll + l;
                out[idx] = x[idx] + bias[r] + acc[ns][r];
            }
        }
    }
}

// ---------------- launch ----------------
extern "C" void kernel_launch(void* const* d_in, const int* in_sizes, int n_in,
                              void* d_out, int out_size, void* d_ws, size_t ws_size,
                              hipStream_t stream) {
    const float* x     = (const float*)d_in[0];
    const float* gamma = (const float*)d_in[1];
    const float* beta  = (const float*)d_in[2];
    const float* wq    = (const float*)d_in[3];
    const float* bq    = (const float*)d_in[4];
    const float* wk    = (const float*)d_in[5];
    const float* bk    = (const float*)d_in[6];
    const float* wv    = (const float*)d_in[7];
    const float* bv    = (const float*)d_in[8];
    const float* wp    = (const float*)d_in[9];
    const float* bp    = (const float*)d_in[10];
    float* out = (float*)d_out;
    char* ws = (char*)d_ws;

    float* sums    = (float*)(ws + 0);         // 512 f32 (sum, sumsq)
    float* biasQKV = (float*)(ws + 2048);
    u16*   Wqkv    = (u16*)(ws + 8192);
    u16*   Wp16    = (u16*)(ws + 401408);
    u16*   XT      = (u16*)(ws + 532480);      // [B][L][C] bf16 (8.39MB)
    u16*   QT      = (u16*)(ws + 8921088);
    u16*   KT      = (u16*)(ws + 17309696);
    u16*   V       = (u16*)(ws + 25698304);    // ends at 34086912
    u16*   OT      = XT;                       // alias: XT dead after k_qkv

    // fused path: Opart (16.78MB) + Lpart (128KB) live in ws past V
    const size_t opart_off = 34086912;
    const size_t lpart_off = opart_off + 16777216;
    const size_t needed    = lpart_off + 131072;
    int fused = (ws_size >= needed) ? 1 : 0;
    u16*   Opart = fused ? (u16*)(ws + opart_off) : (u16*)d_out;
    float* Lpart = (float*)(ws + (fused ? lpart_off : opart_off));

    hipMemsetAsync(sums, 0, 2048, stream);
    k_transpose<<<dim3(64, 4, 4), 256, 0, stream>>>(x, XT, sums);
    k_fold<<<1024, 256, 0, stream>>>(wq, bq, wk, bk, wv, bv, wp, gamma, beta,
                                     sums, Wqkv, biasQKV, Wp16);
    k_qkv<<<dim3(64, 4), 256, 0, stream>>>(XT, Wqkv, biasQKV, QT, KT, V);
    k_attn<<<512, 256, 0, stream>>>(QT, KT, V, Opart, Lpart);
    if (!fused)
        k_merge<<<256, 256, 0, stream>>>(Opart, Lpart, OT);
    k_proj<<<dim3(64, 4), 256, 0, stream>>>(OT, Opart, Lpart, fused,
                                            Wp16, bp, x, out);
}

// Round 11
// 228.682 us; speedup vs baseline: 1.1217x; 1.1217x over previous
//
#include <hip/hip_runtime.h>
#include <math.h>

typedef unsigned short u16;
typedef unsigned int u32;
typedef short s16x8 __attribute__((ext_vector_type(8)));   // 8 bf16 (4 VGPRs)
typedef float f32x4 __attribute__((ext_vector_type(4)));   // 4 fp32
typedef float f32x16 __attribute__((ext_vector_type(16))); // 16 fp32 (32x32 acc)

static constexpr int Cc = 256;
static constexpr int Ll = 4096;
static constexpr int Bb = 4;

__device__ __forceinline__ u16 f2b(float f) {
    union { float f; unsigned u; } v; v.f = f;
    unsigned r = v.u + 0x7FFF + ((v.u >> 16) & 1);   // RNE
    return (u16)(r >> 16);
}
__device__ __forceinline__ float b2f(u16 h) {
    union { unsigned u; float f; } v; v.u = ((unsigned)h) << 16; return v.f;
}

// async 16B global->LDS (lds dest = wave-uniform base + lane*16)
__device__ __forceinline__ void gload_lds16(const u16* g, u16* l) {
    __builtin_amdgcn_global_load_lds(
        (const __attribute__((address_space(1))) u32*)g,
        (__attribute__((address_space(3))) u32*)l, 16, 0, 0);
}

// ---------------- Kernel 3': transpose + fused BN partial stats ----------------
__global__ void k_transpose(const float* __restrict__ x, u16* __restrict__ XT,
                            float* __restrict__ sums) {
    int lt = blockIdx.x, ct = blockIdx.y, b = blockIdx.z, t = threadIdx.x;
    int l0 = lt * 64, c0 = ct * 64;
    __shared__ u16 tile[64][65];
    __shared__ float red[2][4][64];
    int ll = t & 63, cb = t >> 6;
    #pragma unroll
    for (int rep = 0; rep < 16; rep++) {
        int cl = cb * 16 + rep;
        tile[cl][ll] = f2b(x[(size_t)(b * Cc + c0 + cl) * Ll + l0 + ll]);
    }
    __syncthreads();
    int cl2 = t & 63, lb = t >> 6;
    float s = 0.f, s2 = 0.f;
    #pragma unroll
    for (int rep = 0; rep < 16; rep++) {
        int ll2 = lb * 16 + rep;
        u16 hv = tile[cl2][ll2];
        XT[(size_t)(b * Ll + l0 + ll2) * Cc + c0 + cl2] = hv;
        float v = b2f(hv);
        s += v; s2 += v * v;
    }
    red[0][lb][cl2] = s;
    red[1][lb][cl2] = s2;
    __syncthreads();
    if (t < 64) {
        float ss = red[0][0][t] + red[0][1][t] + red[0][2][t] + red[0][3][t];
        float ss2 = red[1][0][t] + red[1][1][t] + red[1][2][t] + red[1][3][t];
        atomicAdd(&sums[c0 + t], ss);
        atomicAdd(&sums[256 + c0 + t], ss2);
    }
}

// ---------------- Kernel 2': fold BN into weights (coefs inline from sums) -----
__global__ void k_fold(const float* __restrict__ wq, const float* __restrict__ bq,
                       const float* __restrict__ wk, const float* __restrict__ bk,
                       const float* __restrict__ wv, const float* __restrict__ bv,
                       const float* __restrict__ wp,
                       const float* __restrict__ gamma, const float* __restrict__ beta,
                       const float* __restrict__ sums,
                       u16* __restrict__ Wqkv, float* __restrict__ biasQKV,
                       u16* __restrict__ Wp16) {
    int m = blockIdx.x, t = threadIdx.x;
    if (m >= 768) {
        int row = m - 768;
        Wp16[row * Cc + t] = f2b(wp[row * Cc + t]);
        return;
    }
    const float inv_n = 1.f / (Bb * Ll);
    float mean = sums[t] * inv_n;
    float var  = sums[256 + t] * inv_n - mean * mean;   // biased, as torch BN
    float rstd = rsqrtf(var + 1e-5f);
    float a  = gamma[t] * rstd;          // coefA
    float cB = beta[t] - mean * a;       // coefB
    int type = m >> 8, row = m & 255;
    const float* W  = (type == 0) ? wq : (type == 1) ? wk : wv;
    const float* bs = (type == 0) ? bq : (type == 1) ? bk : bv;
    float wval = W[row * Cc + t];
    float s2 = (type == 0) ? 0.09016844005556021f : 1.0f;  // (1/sqrt(C)) * log2(e)
    Wqkv[m * Cc + t] = f2b(wval * a * s2);
    __shared__ float rs[256];
    rs[t] = wval * cB;
    __syncthreads();
    for (int off = 128; off > 0; off >>= 1) {
        if (t < off) rs[t] += rs[t + off];
        __syncthreads();
    }
    if (t == 0) biasQKV[m] = (bs[row] + rs[0]) * s2;
}

// ---------------- Kernel 4': QKV GEMM, XT staged once, loop over o-tiles ------
__launch_bounds__(256, 2)
__global__ void k_qkv(const u16* __restrict__ XT, const u16* __restrict__ Wqkv,
                      const float* __restrict__ biasQKV,
                      u16* __restrict__ QT, u16* __restrict__ KT, u16* __restrict__ V) {
    int ly = blockIdx.x, b = blockIdx.y;
    int t = threadIdx.x, w = t >> 6, lane = t & 63;
    int l16 = lane & 15, quad = lane >> 4;
    int l0 = ly * 64;
    __shared__ u16 Xs[64][264];
    {
        int row = t >> 2, chunk = t & 3;
        const u16* src = XT + (size_t)(b * Ll + l0 + row) * Cc + chunk * 64;
        u16* dst = &Xs[row][chunk * 64];
        #pragma unroll
        for (int u = 0; u < 8; u++)
            *(uint4*)(dst + u * 8) = *(const uint4*)(src + u * 8);
    }
    __syncthreads();
    for (int ox = 0; ox < 12; ox++) {
        int o0 = ox * 64;
        s16x8 af[8];
        {
            const u16* wrow = Wqkv + (size_t)(o0 + w * 16 + l16) * Cc + quad * 8;
            #pragma unroll
            for (int ks = 0; ks < 8; ks++) af[ks] = *(const s16x8*)(wrow + ks * 32);
        }
        f32x4 acc[4];
        #pragma unroll
        for (int ns = 0; ns < 4; ns++)
            #pragma unroll
            for (int r = 0; r < 4; r++) acc[ns][r] = 0.f;
        #pragma unroll
        for (int ks = 0; ks < 8; ks++) {
            #pragma unroll
            for (int ns = 0; ns < 4; ns++) {
                s16x8 bf = *(const s16x8*)(&Xs[ns * 16 + l16][ks * 32 + quad * 8]);
                acc[ns] = __builtin_amdgcn_mfma_f32_16x16x32_bf16(af[ks], bf, acc[ns], 0, 0, 0);
            }
        }
        int obase = o0 + w * 16 + quad * 4;
        float bias[4];
        #pragma unroll
        for (int r = 0; r < 4; r++) bias[r] = biasQKV[obase + r];
        #pragma unroll
        for (int ns = 0; ns < 4; ns++) {
            int l = l0 + ns * 16 + l16;
            if (ox < 8) {
                u16* dstbase = (ox < 4) ? QT : KT;
                int oo = obase - ((ox < 4) ? 0 : 256);
                ushort4 pk;
                pk.x = f2b(acc[ns][0] + bias[0]);
                pk.y = f2b(acc[ns][1] + bias[1]);
                pk.z = f2b(acc[ns][2] + bias[2]);
                pk.w = f2b(acc[ns][3] + bias[3]);
                *(ushort4*)(dstbase + (size_t)(b * Ll + l) * Cc + oo) = pk;
            } else {
                #pragma unroll
                for (int r = 0; r < 4; r++) {
                    int o = obase + r - 512;
                    V[(size_t)(b * Cc + o) * Ll + l] = f2b(acc[ns][r] + bias[r]);
                }
            }
        }
    }
}

// ---------------- Kernel 5: flash attention, BI=128, 8 waves, 32x32x16 MFMA ----
// 256 blocks = (b x 32 i-tiles(128 rows) x 2 j-halves); 512 threads (8 waves):
// rh=w&3 (row 32-set), ch=w>>2 (col half). Each staged K/V byte now serves 2x
// the Q rows -> DMA and LDS-read per unit work HALVED vs the 64-row version.
// LDS = Ka 32K + Vb 32K + Pss 18K + Lred = 83KB -> 1 block/CU, 8 waves/CU.
__launch_bounds__(512, 2)
__global__ void k_attn(const u16* __restrict__ QT, const u16* __restrict__ KT,
                       const u16* __restrict__ V, u16* __restrict__ Opart,
                       float* __restrict__ Lpart) {
    int id = blockIdx.x;
    int xcd = id & 7, local = id >> 3;      // local 0..31
    int b = xcd >> 1;                       // 2 XCDs per batch: K/V L2-resident
    int u = local * 2 + (xcd & 1);          // 0..63
    int itile = u >> 1;                     // 0..31 (128-row i-tiles)
    int jh = u & 1;
    int t = threadIdx.x, w = t >> 6, lane = t & 63;
    int rh = w & 3, ch = w >> 2;
    int l31 = lane & 31, hi = lane >> 5;    // hi = k-half selector in A/B frags

    __shared__ u16 Ka[16384];        // 32KB: 32 frags (ch 0..1 x ks 0..15) of 1KB
    __shared__ u16 Vbuf[16384];      // 32KB: 32 frags (ctile 0..7 x ksj 0..3)
    __shared__ u16 Pss[128 * 72];    // 128x64 P tile, stride 72 (18KB)
    __shared__ float Lred[4][2][32]; // [rh][ch][row] epilogue l partials

    // Q A-frags: rows itile*128 + rh*32 + l31, k = ks*16 + hi*8 + [0..8)
    s16x8 qf[16];
    {
        const u16* qbase = QT + (size_t)(b * Ll + itile * 128 + rh * 32 + l31) * Cc + hi * 8;
        #pragma unroll
        for (int ks = 0; ks < 16; ks++) qf[ks] = *(const s16x8*)(qbase + ks * 16);
    }

    // staging pointers; frag g = R*8 + w (R 0..3 -> 32 frags each for K and V)
    const u16* kptr[4];
    const u16* vptr[4];
    #pragma unroll
    for (int R = 0; R < 4; R++) {
        int g = R * 8 + w;
        int gch = g >> 4, gks = g & 15;   // K frag: col-tile, k-step
        kptr[R] = KT + (size_t)(b * Ll + jh * 2048 + gch * 32 + l31) * Cc + gks * 16 + hi * 8;
        int gct = g >> 2, gkj = g & 3;    // V frag: c-tile, j-step
        vptr[R] = V + (size_t)(b * Cc + gct * 32 + l31) * Ll + jh * 2048 + gkj * 16 + hi * 8;
    }

    // prologue: issue K(0) and V(0)
    #pragma unroll
    for (int R = 0; R < 4; R++) {
        gload_lds16(kptr[R], &Ka[(size_t)((R * 8 + w) * 64) * 8]);
        kptr[R] += 64 * Cc;
    }
    #pragma unroll
    for (int R = 0; R < 4; R++) {
        gload_lds16(vptr[R], &Vbuf[(size_t)((R * 8 + w) * 64) * 8]);
        vptr[R] += 64;
    }

    f32x16 of16[4];
    #pragma unroll
    for (int ct = 0; ct < 4; ct++)
        #pragma unroll
        for (int r = 0; r < 16; r++) of16[ct][r] = 0.f;
    f32x16 lsr;                      // C-layout l partials: col ch*32+l31, row reg
    #pragma unroll
    for (int r = 0; r < 16; r++) lsr[r] = 0.f;

    __syncthreads();   // P0: drains K(0), V(0)

    for (int it = 0; it < 32; it++) {
        // ---- phase A: S quadrant = Q K^T (two interleaved acc chains) ----
        f32x16 s0, s1;
        #pragma unroll
        for (int r = 0; r < 16; r++) { s0[r] = 0.f; s1[r] = 0.f; }
        #pragma unroll
        for (int ks = 0; ks < 16; ks += 2) {
            s16x8 bf0 = *(const s16x8*)(&Ka[(size_t)((ch * 16 + ks) * 64 + lane) * 8]);
            s16x8 bf1 = *(const s16x8*)(&Ka[(size_t)((ch * 16 + ks + 1) * 64 + lane) * 8]);
            s0 = __builtin_amdgcn_mfma_f32_32x32x16_bf16(qf[ks], bf0, s0, 0, 0, 0);
            s1 = __builtin_amdgcn_mfma_f32_32x32x16_bf16(qf[ks + 1], bf1, s1, 0, 0, 0);
        }
        // ---- softmax (fixed m=0): P = exp2(s); l partial in-register ----
        #pragma unroll
        for (int reg = 0; reg < 16; reg++) {
            float p = __builtin_amdgcn_exp2f(s0[reg] + s1[reg]);
            lsr[reg] += p;
            int row_local = (reg & 3) + 8 * (reg >> 2) + 4 * hi;
            Pss[(rh * 32 + row_local) * 72 + ch * 32 + l31] = f2b(p);
        }
        __syncthreads();   // M: Ka reads done; Pss visible; drains V(it)
        if (it < 31) {
            #pragma unroll
            for (int R = 0; R < 4; R++) {
                gload_lds16(kptr[R], &Ka[(size_t)((R * 8 + w) * 64) * 8]);
                kptr[R] += 64 * Cc;
            }
        }
        // ---- phase B: O += P * V^T ----
        #pragma unroll
        for (int ksj = 0; ksj < 4; ksj++) {
            s16x8 pa = *(const s16x8*)(&Pss[(rh * 32 + l31) * 72 + ksj * 16 + hi * 8]);
            #pragma unroll
            for (int ct = 0; ct < 4; ct++) {
                s16x8 bf = *(const s16x8*)(&Vbuf[(size_t)(((ch * 4 + ct) * 4 + ksj) * 64 + lane) * 8]);
                of16[ct] = __builtin_amdgcn_mfma_f32_32x32x16_bf16(pa, bf, of16[ct], 0, 0, 0);
            }
        }
        __syncthreads();   // B: Vbuf+Pss reads done; drains K(it+1)
        if (it < 31) {
            #pragma unroll
            for (int R = 0; R < 4; R++) {
                gload_lds16(vptr[R], &Vbuf[(size_t)((R * 8 + w) * 64) * 8]);
                vptr[R] += 64;
            }
        }
    }
    // epilogue: reduce lsr across this wave's 32 cols, combine ch halves via LDS
    #pragma unroll
    for (int reg = 0; reg < 16; reg++) {
        float v = lsr[reg];
        #pragma unroll
        for (int off = 16; off > 0; off >>= 1) v += __shfl_xor(v, off);
        int row_local = (reg & 3) + 8 * (reg >> 2) + 4 * hi;
        if (l31 == 0) Lred[rh][ch][row_local] = v;
    }
    __syncthreads();
    int mi0 = (jh * 4 + b) * Ll + itile * 128 + rh * 32;
    if (ch == 0 && lane < 32)
        Lpart[mi0 + lane] = Lred[rh][0][lane] + Lred[rh][1][lane];
    #pragma unroll
    for (int ct = 0; ct < 4; ct++) {
        #pragma unroll
        for (int reg = 0; reg < 16; reg++) {
            int row_local = (reg & 3) + 8 * (reg >> 2) + 4 * hi;
            Opart[(size_t)(mi0 + row_local) * 256 + ch * 128 + ct * 32 + l31] =
                f2b(of16[ct][reg]);
        }
    }
}

// ---------------- Kernel 5b (fallback): merge two j-half partials -> OT ---------
__global__ void k_merge(const u16* __restrict__ Opart, const float* __restrict__ Lpart,
                        u16* __restrict__ OT) {
    int id = blockIdx.x, t = threadIdx.x;
    int b = id >> 6, itile = id & 63;
    int row = t >> 2, seg = t & 3;
    size_t i0 = ((size_t)(0 + b) * 64 + itile) * 64 + row;
    size_t i1 = ((size_t)(4 + b) * 64 + itile) * 64 + row;
    float inv = 1.f / (Lpart[i0] + Lpart[i1]);
    const u16* p0 = Opart + i0 * 256 + seg * 64;
    const u16* p1 = Opart + i1 * 256 + seg * 64;
    u16* dst = OT + (size_t)(b * Ll + itile * 64 + row) * Cc + seg * 64;
    #pragma unroll
    for (int k = 0; k < 8; k++) {
        ushort4 a0 = *(const ushort4*)(p0 + k * 8 + 0);
        ushort4 b0 = *(const ushort4*)(p0 + k * 8 + 4);
        ushort4 a1 = *(const ushort4*)(p1 + k * 8 + 0);
        ushort4 b1 = *(const ushort4*)(p1 + k * 8 + 4);
        ushort4 oA, oB;
        oA.x = f2b((b2f(a0.x) + b2f(a1.x)) * inv);
        oA.y = f2b((b2f(a0.y) + b2f(a1.y)) * inv);
        oA.z = f2b((b2f(a0.z) + b2f(a1.z)) * inv);
        oA.w = f2b((b2f(a0.w) + b2f(a1.w)) * inv);
        oB.x = f2b((b2f(b0.x) + b2f(b1.x)) * inv);
        oB.y = f2b((b2f(b0.y) + b2f(b1.y)) * inv);
        oB.z = f2b((b2f(b0.z) + b2f(b1.z)) * inv);
        oB.w = f2b((b2f(b0.w) + b2f(b1.w)) * inv);
        *(ushort4*)(dst + k * 8 + 0) = oA;
        *(ushort4*)(dst + k * 8 + 4) = oB;
    }
}

// ---------------- Kernel 6': projection, OT staged once, loop over o-tiles ------
__launch_bounds__(256, 2)
__global__ void k_proj(const u16* __restrict__ OT, const u16* __restrict__ Opart,
                       const float* __restrict__ Lpart, int fused,
                       const u16* __restrict__ Wp16,
                       const float* __restrict__ bp, const float* __restrict__ x,
                       float* __restrict__ out) {
    int ly = blockIdx.x, b = blockIdx.y;
    int t = threadIdx.x, w = t >> 6, lane = t & 63;
    int l16 = lane & 15, quad = lane >> 4;
    int l0 = ly * 64;
    __shared__ u16 Os[64][264];
    {
        int row = t >> 2, chunk = t & 3;
        u16* dst = &Os[row][chunk * 64];
        if (fused) {
            size_t i0 = ((size_t)(0 + b) * Ll + l0 + row);
            size_t i1 = ((size_t)(4 + b) * Ll + l0 + row);
            float inv = 1.f / (Lpart[i0] + Lpart[i1]);
            const u16* p0 = Opart + i0 * 256 + chunk * 64;
            const u16* p1 = Opart + i1 * 256 + chunk * 64;
            #pragma unroll
            for (int k = 0; k < 8; k++) {
                ushort4 a0 = *(const ushort4*)(p0 + k * 8 + 0);
                ushort4 b0 = *(const ushort4*)(p0 + k * 8 + 4);
                ushort4 a1 = *(const ushort4*)(p1 + k * 8 + 0);
                ushort4 b1 = *(const ushort4*)(p1 + k * 8 + 4);
                ushort4 oA, oB;
                oA.x = f2b((b2f(a0.x) + b2f(a1.x)) * inv);
                oA.y = f2b((b2f(a0.y) + b2f(a1.y)) * inv);
                oA.z = f2b((b2f(a0.z) + b2f(a1.z)) * inv);
                oA.w = f2b((b2f(a0.w) + b2f(a1.w)) * inv);
                oB.x = f2b((b2f(b0.x) + b2f(b1.x)) * inv);
                oB.y = f2b((b2f(b0.y) + b2f(b1.y)) * inv);
                oB.z = f2b((b2f(b0.z) + b2f(b1.z)) * inv);
                oB.w = f2b((b2f(b0.w) + b2f(b1.w)) * inv);
                *(ushort4*)(dst + k * 8 + 0) = oA;
                *(ushort4*)(dst + k * 8 + 4) = oB;
            }
        } else {
            const u16* src = OT + (size_t)(b * Ll + l0 + row) * Cc + chunk * 64;
            #pragma unroll
            for (int u = 0; u < 8; u++)
                *(uint4*)(dst + u * 8) = *(const uint4*)(src + u * 8);
        }
    }
    __syncthreads();
    for (int ox = 0; ox < 4; ox++) {
        int o0 = ox * 64;
        s16x8 af[8];
        {
            const u16* wrow = Wp16 + (size_t)(o0 + w * 16 + l16) * Cc + quad * 8;
            #pragma unroll
            for (int ks = 0; ks < 8; ks++) af[ks] = *(const s16x8*)(wrow + ks * 32);
        }
        f32x4 acc[4];
        #pragma unroll
        for (int ns = 0; ns < 4; ns++)
            #pragma unroll
            for (int r = 0; r < 4; r++) acc[ns][r] = 0.f;
        #pragma unroll
        for (int ks = 0; ks < 8; ks++) {
            #pragma unroll
            for (int ns = 0; ns < 4; ns++) {
                s16x8 bf = *(const s16x8*)(&Os[ns * 16 + l16][ks * 32 + quad * 8]);
                acc[ns] = __builtin_amdgcn_mfma_f32_16x16x32_bf16(af[ks], bf, acc[ns], 0, 0, 0);
            }
        }
        int ob = o0 + w * 16 + quad * 4;
        float bias[4];
        #pragma unroll
        for (int r = 0; r < 4; r++) bias[r] = bp[ob + r];
        #pragma unroll
        for (int ns = 0; ns < 4; ns++) {
            #pragma unroll
            for (int r = 0; r < 4; r++) {
                int o = ob + r;
                int l = l0 + ns * 16 + l16;
                size_t idx = (size_t)(b * Cc + o) * Ll + l;
                out[idx] = x[idx] + bias[r] + acc[ns][r];
            }
        }
    }
}

// ---------------- launch ----------------
extern "C" void kernel_launch(void* const* d_in, const int* in_sizes, int n_in,
                              void* d_out, int out_size, void* d_ws, size_t ws_size,
                              hipStream_t stream) {
    const float* x     = (const float*)d_in[0];
    const float* gamma = (const float*)d_in[1];
    const float* beta  = (const float*)d_in[2];
    const float* wq    = (const float*)d_in[3];
    const float* bq    = (const float*)d_in[4];
    const float* wk    = (const float*)d_in[5];
    const float* bk    = (const float*)d_in[6];
    const float* wv    = (const float*)d_in[7];
    const float* bv    = (const float*)d_in[8];
    const float* wp    = (const float*)d_in[9];
    const float* bp    = (const float*)d_in[10];
    float* out = (float*)d_out;
    char* ws = (char*)d_ws;

    float* sums    = (float*)(ws + 0);         // 512 f32 (sum, sumsq)
    float* biasQKV = (float*)(ws + 2048);
    u16*   Wqkv    = (u16*)(ws + 8192);
    u16*   Wp16    = (u16*)(ws + 401408);
    u16*   XT      = (u16*)(ws + 532480);      // [B][L][C] bf16 (8.39MB)
    u16*   QT      = (u16*)(ws + 8921088);
    u16*   KT      = (u16*)(ws + 17309696);
    u16*   V       = (u16*)(ws + 25698304);    // ends at 34086912
    u16*   OT      = XT;                       // alias: XT dead after k_qkv

    // fused path: Opart (16.78MB) + Lpart (128KB) live in ws past V
    const size_t opart_off = 34086912;
    const size_t lpart_off = opart_off + 16777216;
    const size_t needed    = lpart_off + 131072;
    int fused = (ws_size >= needed) ? 1 : 0;
    u16*   Opart = fused ? (u16*)(ws + opart_off) : (u16*)d_out;
    float* Lpart = (float*)(ws + (fused ? lpart_off : opart_off));

    hipMemsetAsync(sums, 0, 2048, stream);
    k_transpose<<<dim3(64, 4, 4), 256, 0, stream>>>(x, XT, sums);
    k_fold<<<1024, 256, 0, stream>>>(wq, bq, wk, bk, wv, bv, wp, gamma, beta,
                                     sums, Wqkv, biasQKV, Wp16);
    k_qkv<<<dim3(64, 4), 256, 0, stream>>>(XT, Wqkv, biasQKV, QT, KT, V);
    k_attn<<<256, 512, 0, stream>>>(QT, KT, V, Opart, Lpart);
    if (!fused)
        k_merge<<<256, 256, 0, stream>>>(Opart, Lpart, OT);
    k_proj<<<dim3(64, 4), 256, 0, stream>>>(OT, Opart, Lpart, fused,
                                            Wp16, bp, x, out);
}